// Round 1
// baseline (457.736 us; speedup 1.0000x reference)
//
#include <hip/hip_runtime.h>

// FM_FTRL == two unit-lower-triangular solves (R1/R2 analysis):
//   alpha_i = -2eta*(x_0.x_i - q0*q_i)  (closed form, K_A=1; alpha_0 = 1)
//   (I+Lh)s = r, Lh[i,j] = 2eta*(x_j.x_i) j<i
//   r_i = 2*(alpha_i^2*T0 - b_i) (i>=1), r_0 = 2*(s0 + T0 - b_0)
//   preds = s/2 + b ;  K_B=2: s ~= r - L r + L^2 r
// This round: CC 100->40 (chunking is exact at any CC; gram FLOPs ~ N*CC/2),
// grid 200->500 blocks, 2 blocks/CU via __launch_bounds__(1024,8), and
// double-buffered global_load_lds staging in k_gram (loads for stage s+1
// issued before compute of stage s; barrier vmcnt(0) is the only drain).

#define NN 20000
#define CC 40
#define NCH 500
#define ETA2 2e-5f

// ws float offsets (total ~9.9 MB; R4 proved >=10.7 MB available)
#define OFF_GRAM 0L          // 500 chunks x 780 packed lower-tri
#define OFF_ZR   390016L
#define OFF_Z1   902016L
#define OFF_S1   1414016L
#define OFF_S2   1926016L
#define OFF_SCLP 2438016L    // [0..31] T0 partials, [32] s0
#define OFF_ACC  2438056L
#define OFF_TV   2458056L

__device__ __forceinline__ void async16(const float* g, float* l) {
  __builtin_amdgcn_global_load_lds(
      (const __attribute__((address_space(1))) void*)g,
      (__attribute__((address_space(3))) void*)l, 16, 0, 0);
}

// ---------------- k0: T0/s0 partials + b-copy ------------------------------
__global__ __launch_bounds__(1024) void k_init(
    const float* __restrict__ At, const float* __restrict__ bvec,
    const float* __restrict__ w1, const float* __restrict__ W2,
    float* __restrict__ out, float* __restrict__ scalp) {
  __shared__ float x0s[1024];
  __shared__ float part[16];
  const int bid = blockIdx.x, t = threadIdx.x;
  const int wid = t >> 6, lane = t & 63;

  if (bid < 32) {  // T0 partial over 16 W2 rows
    x0s[t] = (t < 1023) ? At[(long)t * NN] : 0.f;
    __syncthreads();
    const int row = bid * 16 + wid;
    float p = 0.f;
#pragma unroll
    for (int k = 0; k < 16; ++k) {
      const int ci = k * 64 + lane;
      if (ci < 1023) p = fmaf(W2[(long)row * 1023 + ci], x0s[ci], p);
    }
#pragma unroll
    for (int o = 32; o > 0; o >>= 1) p += __shfl_down(p, o);
    if (lane == 0) part[wid] = p * p;
    __syncthreads();
    if (t == 0) {
      float s = 0.f;
#pragma unroll
      for (int k = 0; k < 16; ++k) s += part[k];
      scalp[bid] = s;
    }
  } else if (bid == 32) {  // s0 = w1 . x0 (full 1024)
    float p = w1[t] * At[(long)t * NN];
#pragma unroll
    for (int o = 32; o > 0; o >>= 1) p += __shfl_down(p, o);
    if (lane == 0) part[wid] = p;
    __syncthreads();
    if (t == 0) {
      float s = 0.f;
#pragma unroll
      for (int k = 0; k < 16; ++k) s += part[k];
      scalp[32] = s;
    }
  } else {  // b-copy: 20 blocks x 1000
    const int i = (bid - 33) * 1000 + t;
    if (t < 1000) out[NN + i] = bvec[i];
  }
}

// ---------------- k1: packed chunk Grams + alpha + r + Zr ------------------
// CC=40: stage = 128 rows x 40 floats = 1280 float4 = 20,480B, double-buffered.
// gram: 55 lower-tri 4x4 tiles x 4 e-bands = 220 threads; u: 4 bands x 40.
struct GramSh {
  __align__(16) float xt[2][5120];  // 40,960 B double-buffered stage
  float scr[2640];                  // bands 1..3 partials: 3 x 55 x 16
  float x0s[1024];
  float up[160];
  __align__(16) float rs[CC];
  float sc[2];
};
static_assert(sizeof(GramSh) <= 64 * 1024, "LDS overflow");

__global__ __launch_bounds__(1024, 8) void k_gram(
    const float* __restrict__ At, const float* __restrict__ bvec,
    float* __restrict__ gram, float* __restrict__ Zr,
    const float* __restrict__ scalp, float* __restrict__ acc) {
  __shared__ GramSh sh;
  const int c = blockIdx.x, t = threadIdx.x;
  const long i0 = (long)c * CC;

  sh.x0s[t] = At[(long)t * NN];
  if (t == 0) {
    float T = 0.f;
#pragma unroll
    for (int k = 0; k < 32; ++k) T += scalp[k];
    sh.sc[0] = T;
    sh.sc[1] = scalp[32];
  }

  // staging addresses: idx=t and idx=1024+t; LDS float offset = 4*idx (linear)
  const float* g1 = At + (long)(t / 10) * NN + i0 + 4 * (t % 10);
  const float* g2 =
      At + (long)((1024 + t) / 10) * NN + i0 + 4 * ((1024 + t) % 10);

  // roles
  const bool act = (t < 220);
  int a = 0, bb = 0, band = 0, tile = 0;
  if (act) {
    tile = t % 55; band = t / 55;
    int r = tile; while (r > a) { r -= ++a; } bb = r;
  }
  const bool uact = (t >= 220 && t < 380);
  const int uz = t - 220;
  const int uband = uz / 40, ui = uz - uband * 40;
  float uacc = 0.f;

  float ac[4][4];
#pragma unroll
  for (int r = 0; r < 4; ++r)
#pragma unroll
    for (int s = 0; s < 4; ++s) ac[r][s] = 0.f;

  // prologue: stage 0 -> buf 0 (barrier's vmcnt(0) drain makes it ready)
  async16(g1, &sh.xt[0][4 * t]);
  if (t < 256) async16(g2, &sh.xt[0][4096 + 4 * t]);
  __syncthreads();

  const int e0g = band * 32;
  const int e0u = uband * 32;

  for (int st = 0; st < 8; ++st) {
    const float* __restrict__ xs = sh.xt[st & 1];
    if (st < 7) {  // issue next stage into other buffer; overlaps compute
      const long adv = (long)(st + 1) * (128L * NN);
      float* nb = sh.xt[(st + 1) & 1];
      async16(g1 + adv, &nb[4 * t]);
      if (t < 256) async16(g2 + adv, &nb[4096 + 4 * t]);
    }
    if (act) {
#pragma unroll 4
      for (int le = e0g; le < e0g + 32; ++le) {
        const float* row = xs + le * 40;
        const float4 ra = *(const float4*)(row + 4 * a);
        const float4 rb = *(const float4*)(row + 4 * bb);
        ac[0][0] = fmaf(ra.x, rb.x, ac[0][0]); ac[0][1] = fmaf(ra.x, rb.y, ac[0][1]);
        ac[0][2] = fmaf(ra.x, rb.z, ac[0][2]); ac[0][3] = fmaf(ra.x, rb.w, ac[0][3]);
        ac[1][0] = fmaf(ra.y, rb.x, ac[1][0]); ac[1][1] = fmaf(ra.y, rb.y, ac[1][1]);
        ac[1][2] = fmaf(ra.y, rb.z, ac[1][2]); ac[1][3] = fmaf(ra.y, rb.w, ac[1][3]);
        ac[2][0] = fmaf(ra.z, rb.x, ac[2][0]); ac[2][1] = fmaf(ra.z, rb.y, ac[2][1]);
        ac[2][2] = fmaf(ra.z, rb.z, ac[2][2]); ac[2][3] = fmaf(ra.z, rb.w, ac[2][3]);
        ac[3][0] = fmaf(ra.w, rb.x, ac[3][0]); ac[3][1] = fmaf(ra.w, rb.y, ac[3][1]);
        ac[3][2] = fmaf(ra.w, rb.z, ac[3][2]); ac[3][3] = fmaf(ra.w, rb.w, ac[3][3]);
      }
    } else if (uact) {
#pragma unroll 4
      for (int le = e0u; le < e0u + 32; ++le)
        uacc = fmaf(xs[le * 40 + ui], sh.x0s[st * 128 + le], uacc);
    }
    __syncthreads();
  }
  if (uact) sh.up[uz] = uacc;
  __syncthreads();

  // alpha (closed form) -> r ; q row = stage-7 local row 127 (buf 1), intact
  if (t < CC) {
    const long gi = i0 + t;
    const float uu = sh.up[t] + sh.up[40 + t] + sh.up[80 + t] + sh.up[120 + t];
    const float qi = sh.xt[1][127 * 40 + t];
    const float q0 = sh.x0s[1023];
    const float al = (gi == 0) ? 1.f : -ETA2 * (uu - q0 * qi);
    const float T0 = sh.sc[0], s0v = sh.sc[1];
    const float bv = bvec[gi];
    float r = 2.f * fmaf(al * al, T0, -bv);
    if (gi == 0) r = 2.f * (s0v + T0 - bv);
    sh.rs[t] = r;
    acc[gi] = r;
  }
  if (act && band > 0) {  // stash band partials for band-0 finalize
#pragma unroll
    for (int r = 0; r < 4; ++r)
#pragma unroll
      for (int s = 0; s < 4; ++s)
        sh.scr[(band - 1) * 880 + tile * 16 + r * 4 + s] = ac[r][s];
  }
  __syncthreads();

  // Zr[c][e] = sum_j r_j X[e][i0+j]  (chunk rows are L2-hot)
  {
    const float* xr = At + (long)t * NN + i0;
    float z = 0.f;
#pragma unroll
    for (int j4 = 0; j4 < 10; ++j4) {
      const float4 x = *(const float4*)(xr + 4 * j4);
      const float4 rq = *(const float4*)&sh.rs[4 * j4];
      z = fmaf(x.x, rq.x, z); z = fmaf(x.y, rq.y, z);
      z = fmaf(x.z, rq.z, z); z = fmaf(x.w, rq.w, z);
    }
    Zr[(long)c * 1024 + t] = z;
  }

  if (act && band == 0) {  // packed store (j<i only), 4-band sum
    float* gp = gram + (long)c * 780;
#pragma unroll
    for (int r = 0; r < 4; ++r) {
      const int row = 4 * a + r;
      const int base = row * (row - 1) / 2;
#pragma unroll
      for (int s = 0; s < 4; ++s) {
        const int col = 4 * bb + s;
        if (col < row)
          gp[base + col] = ac[r][s] + sh.scr[tile * 16 + r * 4 + s] +
                           sh.scr[880 + tile * 16 + r * 4 + s] +
                           sh.scr[1760 + tile * 16 + r * 4 + s];
      }
    }
  }
}

// ---------------- scan: S[c][e] = sum_{cp<c} Z[cp][e] ----------------------
__global__ __launch_bounds__(64) void k_scan(const float* __restrict__ Z,
                                             float* __restrict__ S) {
  const int e = blockIdx.x * 64 + threadIdx.x;
  float s = 0.f;
#pragma unroll 20
  for (int c = 0; c < NCH; ++c) {
    S[(long)c * 1024 + e] = s;
    s += Z[(long)c * 1024 + e];
  }
}

// ---------------- term: w = -(L v)  --------------------------------------
// LAST=false: v = r (acc), w = t1 ; tvec=t1, acc=r+t1, Z1.
// LAST=true : v = t1 (tvec), w = t2 ; out = 0.5*(acc+t2) + b.
template <bool LAST>
__global__ __launch_bounds__(1024, 8) void k_term(
    const float* __restrict__ At, const float* __restrict__ bvec,
    const float* __restrict__ gram, const float* __restrict__ S,
    float* __restrict__ Z1, float* __restrict__ acc, float* __restrict__ tvec,
    float* __restrict__ out) {
  __shared__ float Sm[1024];
  __shared__ float red[1024];
  __shared__ __align__(16) float vvs[CC], wvs[CC];
  const int c = blockIdx.x, t = threadIdx.x;
  const long i0 = (long)c * CC;

  Sm[t] = S[(long)c * 1024 + t];
  if (t < CC) vvs[t] = LAST ? tvec[i0 + t] : acc[i0 + t];
  __syncthreads();

  // sweep1: dot_i = x_i . S  (16 e-bands x 64 lanes)
  {
    const int ti = t & 63, te = t >> 6;
    float p = 0.f;
    if (ti < CC) {
      const float* col = At + i0 + ti;
      const int e0 = te * 64;
#pragma unroll 8
      for (int e = e0; e < e0 + 64; ++e) p = fmaf(col[(long)e * NN], Sm[e], p);
    }
    red[t] = p;
  }
  __syncthreads();

  if (t < CC) {
    const int i = t;
    float dot = 0.f;
#pragma unroll
    for (int k = 0; k < 16; ++k) dot += red[k * 64 + i];
    const float* grow = gram + (long)c * 780 + i * (i - 1) / 2;
    float g = 0.f;
#pragma unroll 4
    for (int j = 0; j < i; ++j) g = fmaf(grow[j], vvs[j], g);
    const float w = -ETA2 * (dot + g);
    if (LAST) {
      out[i0 + i] = fmaf(0.5f, acc[i0 + i] + w, bvec[i0 + i]);
    } else {
      wvs[i] = w;
      tvec[i0 + i] = w;
      acc[i0 + i] += w;
    }
  }
  if (!LAST) {
    __syncthreads();
    const float* xr = At + (long)t * NN + i0;
    float z = 0.f;
#pragma unroll
    for (int j4 = 0; j4 < 10; ++j4) {
      const float4 x = *(const float4*)(xr + 4 * j4);
      const float4 wq = *(const float4*)&wvs[4 * j4];
      z = fmaf(x.x, wq.x, z); z = fmaf(x.y, wq.y, z);
      z = fmaf(x.z, wq.z, z); z = fmaf(x.w, wq.w, z);
    }
    Z1[(long)c * 1024 + t] = z;
  }
}

extern "C" void kernel_launch(void* const* d_in, const int* in_sizes, int n_in,
                              void* d_out, int out_size, void* d_ws,
                              size_t ws_size, hipStream_t stream) {
  const float* At = (const float*)d_in[0];  // (1024, 20000) row-major
  const float* b  = (const float*)d_in[1];
  const float* w1 = (const float*)d_in[2];
  const float* W2 = (const float*)d_in[3];  // (512, 1023) row-major
  float* out = (float*)d_out;
  float* ws = (float*)d_ws;

  float* gram  = ws + OFF_GRAM;
  float* Zr    = ws + OFF_ZR;
  float* Z1    = ws + OFF_Z1;
  float* S1    = ws + OFF_S1;
  float* S2    = ws + OFF_S2;
  float* scalp = ws + OFF_SCLP;
  float* acc   = ws + OFF_ACC;
  float* tvec  = ws + OFF_TV;

  k_init<<<dim3(53), dim3(1024), 0, stream>>>(At, b, w1, W2, out, scalp);
  k_gram<<<dim3(NCH), dim3(1024), 0, stream>>>(At, b, gram, Zr, scalp, acc);
  k_scan<<<dim3(16), dim3(64), 0, stream>>>(Zr, S1);
  k_term<false><<<dim3(NCH), dim3(1024), 0, stream>>>(At, b, gram, S1, Z1, acc,
                                                      tvec, out);
  k_scan<<<dim3(16), dim3(64), 0, stream>>>(Z1, S2);
  k_term<true><<<dim3(NCH), dim3(1024), 0, stream>>>(At, b, gram, S2, Z1, acc,
                                                     tvec, out);
}

// Round 2
// 228.772 us; speedup vs baseline: 2.0008x; 2.0008x over previous
//
#include <hip/hip_runtime.h>

// FM_FTRL == two unit-lower-triangular solves (R1/R2 analysis):
//   alpha_i = -2eta*(x_0.x_i - q0*q_i)  (closed form, K_A=1; alpha_0 = 1)
//   (I+Lh)s = r, Lh[i,j] = 2eta*(x_j.x_i) j<i
//   r_i = 2*(alpha_i^2*T0 - b_i) (i>=1), r_0 = 2*(s0 + T0 - b_0)
//   preds = s/2 + b ;  K_B=2: s ~= r - L r + L^2 r
// R1 result: CC=40 improved non-scan kernels (~213us) but k_scan went fully
// latency-serial (122.7us each: 500 iters x ~600cy HBM latency, 16 waves).
// This round: parallel two-pass grouped scan. 16 c-groups x 64 e per block,
// register-batched loads (8 in flight) -> serial chain 500 -> 32 elems.

#define NN 20000
#define CC 40
#define NCH 500
#define ETA2 2e-5f

// ws float offsets (total ~9.9 MB; R4 proved >=10.7 MB available)
#define OFF_GRAM 0L          // 500 chunks x 780 packed lower-tri
#define OFF_ZR   390016L
#define OFF_Z1   902016L
#define OFF_S1   1414016L
#define OFF_S2   1926016L
#define OFF_SCLP 2438016L    // [0..31] T0 partials, [32] s0
#define OFF_ACC  2438056L
#define OFF_TV   2458056L

__device__ __forceinline__ void async16(const float* g, float* l) {
  __builtin_amdgcn_global_load_lds(
      (const __attribute__((address_space(1))) void*)g,
      (__attribute__((address_space(3))) void*)l, 16, 0, 0);
}

// ---------------- k0: T0/s0 partials + b-copy ------------------------------
__global__ __launch_bounds__(1024) void k_init(
    const float* __restrict__ At, const float* __restrict__ bvec,
    const float* __restrict__ w1, const float* __restrict__ W2,
    float* __restrict__ out, float* __restrict__ scalp) {
  __shared__ float x0s[1024];
  __shared__ float part[16];
  const int bid = blockIdx.x, t = threadIdx.x;
  const int wid = t >> 6, lane = t & 63;

  if (bid < 32) {  // T0 partial over 16 W2 rows
    x0s[t] = (t < 1023) ? At[(long)t * NN] : 0.f;
    __syncthreads();
    const int row = bid * 16 + wid;
    float p = 0.f;
#pragma unroll
    for (int k = 0; k < 16; ++k) {
      const int ci = k * 64 + lane;
      if (ci < 1023) p = fmaf(W2[(long)row * 1023 + ci], x0s[ci], p);
    }
#pragma unroll
    for (int o = 32; o > 0; o >>= 1) p += __shfl_down(p, o);
    if (lane == 0) part[wid] = p * p;
    __syncthreads();
    if (t == 0) {
      float s = 0.f;
#pragma unroll
      for (int k = 0; k < 16; ++k) s += part[k];
      scalp[bid] = s;
    }
  } else if (bid == 32) {  // s0 = w1 . x0 (full 1024)
    float p = w1[t] * At[(long)t * NN];
#pragma unroll
    for (int o = 32; o > 0; o >>= 1) p += __shfl_down(p, o);
    if (lane == 0) part[wid] = p;
    __syncthreads();
    if (t == 0) {
      float s = 0.f;
#pragma unroll
      for (int k = 0; k < 16; ++k) s += part[k];
      scalp[32] = s;
    }
  } else {  // b-copy: 20 blocks x 1000
    const int i = (bid - 33) * 1000 + t;
    if (t < 1000) out[NN + i] = bvec[i];
  }
}

// ---------------- k1: packed chunk Grams + alpha + r + Zr ------------------
// CC=40: stage = 128 rows x 40 floats = 1280 float4 = 20,480B, double-buffered.
// gram: 55 lower-tri 4x4 tiles x 4 e-bands = 220 threads; u: 4 bands x 40.
struct GramSh {
  __align__(16) float xt[2][5120];  // 40,960 B double-buffered stage
  float scr[2640];                  // bands 1..3 partials: 3 x 55 x 16
  float x0s[1024];
  float up[160];
  __align__(16) float rs[CC];
  float sc[2];
};
static_assert(sizeof(GramSh) <= 64 * 1024, "LDS overflow");

__global__ __launch_bounds__(1024, 8) void k_gram(
    const float* __restrict__ At, const float* __restrict__ bvec,
    float* __restrict__ gram, float* __restrict__ Zr,
    const float* __restrict__ scalp, float* __restrict__ acc) {
  __shared__ GramSh sh;
  const int c = blockIdx.x, t = threadIdx.x;
  const long i0 = (long)c * CC;

  sh.x0s[t] = At[(long)t * NN];
  if (t == 0) {
    float T = 0.f;
#pragma unroll
    for (int k = 0; k < 32; ++k) T += scalp[k];
    sh.sc[0] = T;
    sh.sc[1] = scalp[32];
  }

  // staging addresses: idx=t and idx=1024+t; LDS float offset = 4*idx (linear)
  const float* g1 = At + (long)(t / 10) * NN + i0 + 4 * (t % 10);
  const float* g2 =
      At + (long)((1024 + t) / 10) * NN + i0 + 4 * ((1024 + t) % 10);

  // roles
  const bool act = (t < 220);
  int a = 0, bb = 0, band = 0, tile = 0;
  if (act) {
    tile = t % 55; band = t / 55;
    int r = tile; while (r > a) { r -= ++a; } bb = r;
  }
  const bool uact = (t >= 220 && t < 380);
  const int uz = t - 220;
  const int uband = uz / 40, ui = uz - uband * 40;
  float uacc = 0.f;

  float ac[4][4];
#pragma unroll
  for (int r = 0; r < 4; ++r)
#pragma unroll
    for (int s = 0; s < 4; ++s) ac[r][s] = 0.f;

  // prologue: stage 0 -> buf 0 (barrier's vmcnt(0) drain makes it ready)
  async16(g1, &sh.xt[0][4 * t]);
  if (t < 256) async16(g2, &sh.xt[0][4096 + 4 * t]);
  __syncthreads();

  const int e0g = band * 32;
  const int e0u = uband * 32;

  for (int st = 0; st < 8; ++st) {
    const float* __restrict__ xs = sh.xt[st & 1];
    if (st < 7) {  // issue next stage into other buffer; overlaps compute
      const long adv = (long)(st + 1) * (128L * NN);
      float* nb = sh.xt[(st + 1) & 1];
      async16(g1 + adv, &nb[4 * t]);
      if (t < 256) async16(g2 + adv, &nb[4096 + 4 * t]);
    }
    if (act) {
#pragma unroll 4
      for (int le = e0g; le < e0g + 32; ++le) {
        const float* row = xs + le * 40;
        const float4 ra = *(const float4*)(row + 4 * a);
        const float4 rb = *(const float4*)(row + 4 * bb);
        ac[0][0] = fmaf(ra.x, rb.x, ac[0][0]); ac[0][1] = fmaf(ra.x, rb.y, ac[0][1]);
        ac[0][2] = fmaf(ra.x, rb.z, ac[0][2]); ac[0][3] = fmaf(ra.x, rb.w, ac[0][3]);
        ac[1][0] = fmaf(ra.y, rb.x, ac[1][0]); ac[1][1] = fmaf(ra.y, rb.y, ac[1][1]);
        ac[1][2] = fmaf(ra.y, rb.z, ac[1][2]); ac[1][3] = fmaf(ra.y, rb.w, ac[1][3]);
        ac[2][0] = fmaf(ra.z, rb.x, ac[2][0]); ac[2][1] = fmaf(ra.z, rb.y, ac[2][1]);
        ac[2][2] = fmaf(ra.z, rb.z, ac[2][2]); ac[2][3] = fmaf(ra.z, rb.w, ac[2][3]);
        ac[3][0] = fmaf(ra.w, rb.x, ac[3][0]); ac[3][1] = fmaf(ra.w, rb.y, ac[3][1]);
        ac[3][2] = fmaf(ra.w, rb.z, ac[3][2]); ac[3][3] = fmaf(ra.w, rb.w, ac[3][3]);
      }
    } else if (uact) {
#pragma unroll 4
      for (int le = e0u; le < e0u + 32; ++le)
        uacc = fmaf(xs[le * 40 + ui], sh.x0s[st * 128 + le], uacc);
    }
    __syncthreads();
  }
  if (uact) sh.up[uz] = uacc;
  __syncthreads();

  // alpha (closed form) -> r ; q row = stage-7 local row 127 (buf 1), intact
  if (t < CC) {
    const long gi = i0 + t;
    const float uu = sh.up[t] + sh.up[40 + t] + sh.up[80 + t] + sh.up[120 + t];
    const float qi = sh.xt[1][127 * 40 + t];
    const float q0 = sh.x0s[1023];
    const float al = (gi == 0) ? 1.f : -ETA2 * (uu - q0 * qi);
    const float T0 = sh.sc[0], s0v = sh.sc[1];
    const float bv = bvec[gi];
    float r = 2.f * fmaf(al * al, T0, -bv);
    if (gi == 0) r = 2.f * (s0v + T0 - bv);
    sh.rs[t] = r;
    acc[gi] = r;
  }
  if (act && band > 0) {  // stash band partials for band-0 finalize
#pragma unroll
    for (int r = 0; r < 4; ++r)
#pragma unroll
      for (int s = 0; s < 4; ++s)
        sh.scr[(band - 1) * 880 + tile * 16 + r * 4 + s] = ac[r][s];
  }
  __syncthreads();

  // Zr[c][e] = sum_j r_j X[e][i0+j]  (chunk rows are L2-hot)
  {
    const float* xr = At + (long)t * NN + i0;
    float z = 0.f;
#pragma unroll
    for (int j4 = 0; j4 < 10; ++j4) {
      const float4 x = *(const float4*)(xr + 4 * j4);
      const float4 rq = *(const float4*)&sh.rs[4 * j4];
      z = fmaf(x.x, rq.x, z); z = fmaf(x.y, rq.y, z);
      z = fmaf(x.z, rq.z, z); z = fmaf(x.w, rq.w, z);
    }
    Zr[(long)c * 1024 + t] = z;
  }

  if (act && band == 0) {  // packed store (j<i only), 4-band sum
    float* gp = gram + (long)c * 780;
#pragma unroll
    for (int r = 0; r < 4; ++r) {
      const int row = 4 * a + r;
      const int base = row * (row - 1) / 2;
#pragma unroll
      for (int s = 0; s < 4; ++s) {
        const int col = 4 * bb + s;
        if (col < row)
          gp[base + col] = ac[r][s] + sh.scr[tile * 16 + r * 4 + s] +
                           sh.scr[880 + tile * 16 + r * 4 + s] +
                           sh.scr[1760 + tile * 16 + r * 4 + s];
      }
    }
  }
}

// ---------------- scan: S[c][e] = sum_{cp<c} Z[cp][e] ----------------------
// Two-pass grouped scan: block = 16 c-groups x 64 e-lanes. Pass1 group sums
// (loads register-batched 8-wide for ILP), LDS exclusive offset, pass2
// writes prefixes. Serial chain per thread: 32 (was 500).
__global__ __launch_bounds__(1024) void k_scan(const float* __restrict__ Z,
                                               float* __restrict__ S) {
  __shared__ float gsum[16][64];
  const int t = threadIdx.x;
  const int ei = t & 63, ci = t >> 6;  // ci in 0..15
  const int e = blockIdx.x * 64 + ei;
  const int c0 = ci * 32;
  const int c1 = (c0 + 32 < NCH) ? c0 + 32 : NCH;

  float s = 0.f;
  for (int base = c0; base < c1; base += 8) {
    float v[8];
#pragma unroll
    for (int k = 0; k < 8; ++k) {
      const int c = base + k;
      v[k] = (c < c1) ? Z[(long)c * 1024 + e] : 0.f;
    }
#pragma unroll
    for (int k = 0; k < 8; ++k) s += v[k];
  }
  gsum[ci][ei] = s;
  __syncthreads();

  float off = 0.f;
  for (int k = 0; k < ci; ++k) off += gsum[k][ei];

  s = off;
  for (int base = c0; base < c1; base += 8) {
    float v[8];
#pragma unroll
    for (int k = 0; k < 8; ++k) {
      const int c = base + k;
      v[k] = (c < c1) ? Z[(long)c * 1024 + e] : 0.f;
    }
#pragma unroll
    for (int k = 0; k < 8; ++k) {
      const int c = base + k;
      if (c < c1) S[(long)c * 1024 + e] = s;
      s += v[k];
    }
  }
}

// ---------------- term: w = -(L v)  --------------------------------------
// LAST=false: v = r (acc), w = t1 ; tvec=t1, acc=r+t1, Z1.
// LAST=true : v = t1 (tvec), w = t2 ; out = 0.5*(acc+t2) + b.
template <bool LAST>
__global__ __launch_bounds__(1024, 8) void k_term(
    const float* __restrict__ At, const float* __restrict__ bvec,
    const float* __restrict__ gram, const float* __restrict__ S,
    float* __restrict__ Z1, float* __restrict__ acc, float* __restrict__ tvec,
    float* __restrict__ out) {
  __shared__ float Sm[1024];
  __shared__ float red[1024];
  __shared__ __align__(16) float vvs[CC], wvs[CC];
  const int c = blockIdx.x, t = threadIdx.x;
  const long i0 = (long)c * CC;

  Sm[t] = S[(long)c * 1024 + t];
  if (t < CC) vvs[t] = LAST ? tvec[i0 + t] : acc[i0 + t];
  __syncthreads();

  // sweep1: dot_i = x_i . S  (16 e-bands x 64 lanes)
  {
    const int ti = t & 63, te = t >> 6;
    float p = 0.f;
    if (ti < CC) {
      const float* col = At + i0 + ti;
      const int e0 = te * 64;
#pragma unroll 8
      for (int e = e0; e < e0 + 64; ++e) p = fmaf(col[(long)e * NN], Sm[e], p);
    }
    red[t] = p;
  }
  __syncthreads();

  if (t < CC) {
    const int i = t;
    float dot = 0.f;
#pragma unroll
    for (int k = 0; k < 16; ++k) dot += red[k * 64 + i];
    const float* grow = gram + (long)c * 780 + i * (i - 1) / 2;
    float g = 0.f;
#pragma unroll 4
    for (int j = 0; j < i; ++j) g = fmaf(grow[j], vvs[j], g);
    const float w = -ETA2 * (dot + g);
    if (LAST) {
      out[i0 + i] = fmaf(0.5f, acc[i0 + i] + w, bvec[i0 + i]);
    } else {
      wvs[i] = w;
      tvec[i0 + i] = w;
      acc[i0 + i] += w;
    }
  }
  if (!LAST) {
    __syncthreads();
    const float* xr = At + (long)t * NN + i0;
    float z = 0.f;
#pragma unroll
    for (int j4 = 0; j4 < 10; ++j4) {
      const float4 x = *(const float4*)(xr + 4 * j4);
      const float4 wq = *(const float4*)&wvs[4 * j4];
      z = fmaf(x.x, wq.x, z); z = fmaf(x.y, wq.y, z);
      z = fmaf(x.z, wq.z, z); z = fmaf(x.w, wq.w, z);
    }
    Z1[(long)c * 1024 + t] = z;
  }
}

extern "C" void kernel_launch(void* const* d_in, const int* in_sizes, int n_in,
                              void* d_out, int out_size, void* d_ws,
                              size_t ws_size, hipStream_t stream) {
  const float* At = (const float*)d_in[0];  // (1024, 20000) row-major
  const float* b  = (const float*)d_in[1];
  const float* w1 = (const float*)d_in[2];
  const float* W2 = (const float*)d_in[3];  // (512, 1023) row-major
  float* out = (float*)d_out;
  float* ws = (float*)d_ws;

  float* gram  = ws + OFF_GRAM;
  float* Zr    = ws + OFF_ZR;
  float* Z1    = ws + OFF_Z1;
  float* S1    = ws + OFF_S1;
  float* S2    = ws + OFF_S2;
  float* scalp = ws + OFF_SCLP;
  float* acc   = ws + OFF_ACC;
  float* tvec  = ws + OFF_TV;

  k_init<<<dim3(53), dim3(1024), 0, stream>>>(At, b, w1, W2, out, scalp);
  k_gram<<<dim3(NCH), dim3(1024), 0, stream>>>(At, b, gram, Zr, scalp, acc);
  k_scan<<<dim3(16), dim3(1024), 0, stream>>>(Zr, S1);
  k_term<false><<<dim3(NCH), dim3(1024), 0, stream>>>(At, b, gram, S1, Z1, acc,
                                                      tvec, out);
  k_scan<<<dim3(16), dim3(1024), 0, stream>>>(Z1, S2);
  k_term<true><<<dim3(NCH), dim3(1024), 0, stream>>>(At, b, gram, S2, Z1, acc,
                                                     tvec, out);
}

// Round 3
// 225.723 us; speedup vs baseline: 2.0279x; 1.0135x over previous
//
#include <hip/hip_runtime.h>

// FM_FTRL == two unit-lower-triangular solves (R1/R2 analysis):
//   alpha_i = -2eta*(x_0.x_i - q0*q_i)  (closed form, K_A=1; alpha_0 = 1)
//   (I+Lh)s = r, Lh[i,j] = 2eta*(x_j.x_i) j<i
//   r_i = 2*(alpha_i^2*T0 - b_i) (i>=1), r_0 = 2*(s0 + T0 - b_0)
//   preds = s/2 + b ;  K_B=2: s ~= r - L r + L^2 r
// R2: 228.8us. k_gram=55.5 with NOTHING saturated (VALU 18%, HBM 32%) ->
// barrier vmcnt(0) drain serialized prefetch vs compute (m97 structural
// stall), plus 1024-line strided x0 gather per block (~30MB overfetch).
// R3: reg-staged pipeline + raw asm barrier (no vmcnt drain; loads for
// stage s+1 fly during compute of s), x0 via ws (gathered once in k_init),
// float4 u-compute, wider k_scan (32 blocks, chain 16).

#define NN 20000
#define CC 40
#define NCH 500
#define ETA2 2e-5f

// ws float offsets (total ~9.9 MB)
#define OFF_GRAM 0L          // 500 chunks x 780 packed lower-tri
#define OFF_ZR   390016L
#define OFF_Z1   902016L
#define OFF_S1   1414016L
#define OFF_S2   1926016L
#define OFF_SCLP 2438016L    // [0..31] T0 partials, [32] s0
#define OFF_ACC  2438056L
#define OFF_TV   2458056L
#define OFF_X0   2478080L    // x0 column, contiguous (1024)

// ---------------- k0: T0/s0 partials + x0 stash + b-copy -------------------
__global__ __launch_bounds__(1024) void k_init(
    const float* __restrict__ At, const float* __restrict__ bvec,
    const float* __restrict__ w1, const float* __restrict__ W2,
    float* __restrict__ out, float* __restrict__ scalp,
    float* __restrict__ x0ws) {
  __shared__ float x0s[1024];
  __shared__ float part[16];
  const int bid = blockIdx.x, t = threadIdx.x;
  const int wid = t >> 6, lane = t & 63;

  if (bid < 32) {  // T0 partial over 16 W2 rows
    x0s[t] = (t < 1023) ? At[(long)t * NN] : 0.f;
    __syncthreads();
    const int row = bid * 16 + wid;
    float p = 0.f;
#pragma unroll
    for (int k = 0; k < 16; ++k) {
      const int ci = k * 64 + lane;
      if (ci < 1023) p = fmaf(W2[(long)row * 1023 + ci], x0s[ci], p);
    }
#pragma unroll
    for (int o = 32; o > 0; o >>= 1) p += __shfl_down(p, o);
    if (lane == 0) part[wid] = p * p;
    __syncthreads();
    if (t == 0) {
      float s = 0.f;
#pragma unroll
      for (int k = 0; k < 16; ++k) s += part[k];
      scalp[bid] = s;
    }
  } else if (bid == 32) {  // s0 = w1 . x0 ; also stash x0 contiguously
    const float xv = At[(long)t * NN];
    x0ws[t] = xv;
    float p = w1[t] * xv;
#pragma unroll
    for (int o = 32; o > 0; o >>= 1) p += __shfl_down(p, o);
    if (lane == 0) part[wid] = p;
    __syncthreads();
    if (t == 0) {
      float s = 0.f;
#pragma unroll
      for (int k = 0; k < 16; ++k) s += part[k];
      scalp[32] = s;
    }
  } else {  // b-copy: 20 blocks x 1000
    const int i = (bid - 33) * 1000 + t;
    if (t < 1000) out[NN + i] = bvec[i];
  }
}

// ---------------- k1: packed chunk Grams + alpha + r + Zr ------------------
// CC=40: stage = 128 rows x 40 floats = 20,480B, double-buffered in LDS but
// REG-staged: stage s+1 is loaded to registers during compute of stage s,
// ds_written at the top of stage s+1. Barrier is raw s_barrier preceded only
// by lgkmcnt(0) -- global loads stay in flight across it (no vmcnt drain).
struct GramSh {
  __align__(16) float xt[2][5120];  // 40,960 B double-buffered stage
  float scr[2640];                  // bands 1..3 partials: 3 x 55 x 16
  float x0s[1024];
  float up[160];
  __align__(16) float rs[CC];
  float sc[2];
};
static_assert(sizeof(GramSh) <= 64 * 1024, "LDS overflow");

__global__ __launch_bounds__(1024, 8) void k_gram(
    const float* __restrict__ At, const float* __restrict__ bvec,
    const float* __restrict__ x0g, float* __restrict__ gram,
    float* __restrict__ Zr, const float* __restrict__ scalp,
    float* __restrict__ acc) {
  __shared__ GramSh sh;
  const int c = blockIdx.x, t = threadIdx.x;
  const long i0 = (long)c * CC;

  sh.x0s[t] = x0g[t];  // contiguous, L3-hot (written once by k_init)
  if (t == 0) {
    float T = 0.f;
#pragma unroll
    for (int k = 0; k < 32; ++k) T += scalp[k];
    sh.sc[0] = T;
    sh.sc[1] = scalp[32];
  }

  // staging addresses: idx=t and idx=1024+t; LDS float offset = 4*idx
  const float* g1 = At + (long)(t / 10) * NN + i0 + 4 * (t % 10);
  const float* g2 =
      At + (long)((1024 + t) / 10) * NN + i0 + 4 * ((1024 + t) % 10);

  // roles: gram = 220 threads (55 lower-tri 4x4 tiles x 4 e-bands);
  //        u    = 40 threads  (10 float4-cols x 4 e-bands)
  const bool act = (t < 220);
  int a = 0, bb = 0, band = 0, tile = 0;
  if (act) {
    tile = t % 55; band = t / 55;
    int r = tile; while (r > a) { r -= ++a; } bb = r;
  }
  const bool uact = (t >= 220 && t < 260);
  const int uz = t - 220;                       // 0..39
  const int uband = uz / 10, uq = uz - uband * 10;
  float4 uac4 = make_float4(0.f, 0.f, 0.f, 0.f);

  float ac[4][4];
#pragma unroll
  for (int r = 0; r < 4; ++r)
#pragma unroll
    for (int s = 0; s < 4; ++s) ac[r][s] = 0.f;

  // prologue: stage 0 into registers
  float4 r1 = *(const float4*)g1;
  float4 r2 = make_float4(0.f, 0.f, 0.f, 0.f);
  if (t < 256) r2 = *(const float4*)g2;

  const int e0g = band * 32;
  const int e0u = uband * 32;

  // Safety of ONE barrier/stage: program order per wave is
  //   ... C(st-1) -> W(st) -> I(st+1) -> B(st) -> C(st) ...
  // When any wave passes B(st), all waves finished W(st), hence C(st-1).
  // W(st+1) targets buf[(st+1)&1] which was last read in C(st-1) -- done.
  // W(st) writes buf[st&1]; concurrent laggards are in C(st-1) on the
  // OTHER buffer. lgkmcnt(0) before s_barrier publishes the ds_writes.
  for (int st = 0; st < 8; ++st) {
    float* nb = sh.xt[st & 1];
    *(float4*)&nb[4 * t] = r1;                       // waits vmcnt for r1 only
    if (t < 256) *(float4*)&nb[4096 + 4 * t] = r2;
    if (st < 7) {  // issue next stage loads; they fly across the barrier
      const long adv = (long)(st + 1) * (128L * NN);
      r1 = *(const float4*)(g1 + adv);
      if (t < 256) r2 = *(const float4*)(g2 + adv);
    }
    asm volatile("s_waitcnt lgkmcnt(0)\n\ts_barrier" ::: "memory");
    const float* __restrict__ xs = sh.xt[st & 1];
    if (act) {
#pragma unroll 4
      for (int le = e0g; le < e0g + 32; ++le) {
        const float* row = xs + le * 40;
        const float4 ra = *(const float4*)(row + 4 * a);
        const float4 rb = *(const float4*)(row + 4 * bb);
        ac[0][0] = fmaf(ra.x, rb.x, ac[0][0]); ac[0][1] = fmaf(ra.x, rb.y, ac[0][1]);
        ac[0][2] = fmaf(ra.x, rb.z, ac[0][2]); ac[0][3] = fmaf(ra.x, rb.w, ac[0][3]);
        ac[1][0] = fmaf(ra.y, rb.x, ac[1][0]); ac[1][1] = fmaf(ra.y, rb.y, ac[1][1]);
        ac[1][2] = fmaf(ra.y, rb.z, ac[1][2]); ac[1][3] = fmaf(ra.y, rb.w, ac[1][3]);
        ac[2][0] = fmaf(ra.z, rb.x, ac[2][0]); ac[2][1] = fmaf(ra.z, rb.y, ac[2][1]);
        ac[2][2] = fmaf(ra.z, rb.z, ac[2][2]); ac[2][3] = fmaf(ra.z, rb.w, ac[2][3]);
        ac[3][0] = fmaf(ra.w, rb.x, ac[3][0]); ac[3][1] = fmaf(ra.w, rb.y, ac[3][1]);
        ac[3][2] = fmaf(ra.w, rb.z, ac[3][2]); ac[3][3] = fmaf(ra.w, rb.w, ac[3][3]);
      }
    } else if (uact) {
#pragma unroll 4
      for (int le = e0u; le < e0u + 32; ++le) {
        const float4 v = *(const float4*)(xs + le * 40 + 4 * uq);
        const float xv = sh.x0s[st * 128 + le];
        uac4.x = fmaf(xv, v.x, uac4.x);
        uac4.y = fmaf(xv, v.y, uac4.y);
        uac4.z = fmaf(xv, v.z, uac4.z);
        uac4.w = fmaf(xv, v.w, uac4.w);
      }
    }
  }
  if (uact) *(float4*)&sh.up[uband * 40 + 4 * uq] = uac4;
  __syncthreads();

  // alpha (closed form) -> r ; q row = stage-7 local row 127 (buf 1), intact
  if (t < CC) {
    const long gi = i0 + t;
    const float uu = sh.up[t] + sh.up[40 + t] + sh.up[80 + t] + sh.up[120 + t];
    const float qi = sh.xt[1][127 * 40 + t];
    const float q0 = sh.x0s[1023];
    const float al = (gi == 0) ? 1.f : -ETA2 * (uu - q0 * qi);
    const float T0 = sh.sc[0], s0v = sh.sc[1];
    const float bv = bvec[gi];
    float r = 2.f * fmaf(al * al, T0, -bv);
    if (gi == 0) r = 2.f * (s0v + T0 - bv);
    sh.rs[t] = r;
    acc[gi] = r;
  }
  if (act && band > 0) {  // stash band partials for band-0 finalize
#pragma unroll
    for (int r = 0; r < 4; ++r)
#pragma unroll
      for (int s = 0; s < 4; ++s)
        sh.scr[(band - 1) * 880 + tile * 16 + r * 4 + s] = ac[r][s];
  }
  __syncthreads();

  // Zr[c][e] = sum_j r_j X[e][i0+j]  (chunk rows are L2-hot)
  {
    const float* xr = At + (long)t * NN + i0;
    float z = 0.f;
#pragma unroll
    for (int j4 = 0; j4 < 10; ++j4) {
      const float4 x = *(const float4*)(xr + 4 * j4);
      const float4 rq = *(const float4*)&sh.rs[4 * j4];
      z = fmaf(x.x, rq.x, z); z = fmaf(x.y, rq.y, z);
      z = fmaf(x.z, rq.z, z); z = fmaf(x.w, rq.w, z);
    }
    Zr[(long)c * 1024 + t] = z;
  }

  if (act && band == 0) {  // packed store (j<i only), 4-band sum
    float* gp = gram + (long)c * 780;
#pragma unroll
    for (int r = 0; r < 4; ++r) {
      const int row = 4 * a + r;
      const int base = row * (row - 1) / 2;
#pragma unroll
      for (int s = 0; s < 4; ++s) {
        const int col = 4 * bb + s;
        if (col < row)
          gp[base + col] = ac[r][s] + sh.scr[tile * 16 + r * 4 + s] +
                           sh.scr[880 + tile * 16 + r * 4 + s] +
                           sh.scr[1760 + tile * 16 + r * 4 + s];
      }
    }
  }
}

// ---------------- scan: S[c][e] = sum_{cp<c} Z[cp][e] ----------------------
// 32 c-groups x 32 e-lanes per block, 32 blocks. Chain/thread = 16, loads
// register-batched 8-wide.
__global__ __launch_bounds__(1024) void k_scan(const float* __restrict__ Z,
                                               float* __restrict__ S) {
  __shared__ float gsum[32][32];
  const int t = threadIdx.x;
  const int ei = t & 31, ci = t >> 5;
  const int e = blockIdx.x * 32 + ei;
  const int c0 = ci * 16;
  const int c1 = (c0 + 16 < NCH) ? c0 + 16 : NCH;

  float s = 0.f;
  for (int base = c0; base < c1; base += 8) {
    float v[8];
#pragma unroll
    for (int k = 0; k < 8; ++k) {
      const int cc = base + k;
      v[k] = (cc < c1) ? Z[(long)cc * 1024 + e] : 0.f;
    }
#pragma unroll
    for (int k = 0; k < 8; ++k) s += v[k];
  }
  gsum[ci][ei] = s;
  __syncthreads();

  float off = 0.f;
#pragma unroll
  for (int k = 0; k < 31; ++k)
    if (k < ci) off += gsum[k][ei];

  s = off;
  for (int base = c0; base < c1; base += 8) {
    float v[8];
#pragma unroll
    for (int k = 0; k < 8; ++k) {
      const int cc = base + k;
      v[k] = (cc < c1) ? Z[(long)cc * 1024 + e] : 0.f;
    }
#pragma unroll
    for (int k = 0; k < 8; ++k) {
      const int cc = base + k;
      if (cc < c1) S[(long)cc * 1024 + e] = s;
      s += v[k];
    }
  }
}

// ---------------- term: w = -(L v)  --------------------------------------
// LAST=false: v = r (acc), w = t1 ; tvec=t1, acc=r+t1, Z1.
// LAST=true : v = t1 (tvec), w = t2 ; out = 0.5*(acc+t2) + b.
template <bool LAST>
__global__ __launch_bounds__(1024, 8) void k_term(
    const float* __restrict__ At, const float* __restrict__ bvec,
    const float* __restrict__ gram, const float* __restrict__ S,
    float* __restrict__ Z1, float* __restrict__ acc, float* __restrict__ tvec,
    float* __restrict__ out) {
  __shared__ float Sm[1024];
  __shared__ float red[1024];
  __shared__ __align__(16) float vvs[CC], wvs[CC];
  const int c = blockIdx.x, t = threadIdx.x;
  const long i0 = (long)c * CC;

  Sm[t] = S[(long)c * 1024 + t];
  if (t < CC) vvs[t] = LAST ? tvec[i0 + t] : acc[i0 + t];
  __syncthreads();

  // sweep1: dot_i = x_i . S  (16 e-bands x 64 lanes)
  {
    const int ti = t & 63, te = t >> 6;
    float p = 0.f;
    if (ti < CC) {
      const float* col = At + i0 + ti;
      const int e0 = te * 64;
#pragma unroll 16
      for (int e = e0; e < e0 + 64; ++e) p = fmaf(col[(long)e * NN], Sm[e], p);
    }
    red[t] = p;
  }
  __syncthreads();

  if (t < CC) {
    const int i = t;
    float dot = 0.f;
#pragma unroll
    for (int k = 0; k < 16; ++k) dot += red[k * 64 + i];
    const float* grow = gram + (long)c * 780 + i * (i - 1) / 2;
    float g = 0.f;
#pragma unroll 8
    for (int j = 0; j < i; ++j) g = fmaf(grow[j], vvs[j], g);
    const float w = -ETA2 * (dot + g);
    if (LAST) {
      out[i0 + i] = fmaf(0.5f, acc[i0 + i] + w, bvec[i0 + i]);
    } else {
      wvs[i] = w;
      tvec[i0 + i] = w;
      acc[i0 + i] += w;
    }
  }
  if (!LAST) {
    __syncthreads();
    const float* xr = At + (long)t * NN + i0;
    float z = 0.f;
#pragma unroll
    for (int j4 = 0; j4 < 10; ++j4) {
      const float4 x = *(const float4*)(xr + 4 * j4);
      const float4 wq = *(const float4*)&wvs[4 * j4];
      z = fmaf(x.x, wq.x, z); z = fmaf(x.y, wq.y, z);
      z = fmaf(x.z, wq.z, z); z = fmaf(x.w, wq.w, z);
    }
    Z1[(long)c * 1024 + t] = z;
  }
}

extern "C" void kernel_launch(void* const* d_in, const int* in_sizes, int n_in,
                              void* d_out, int out_size, void* d_ws,
                              size_t ws_size, hipStream_t stream) {
  const float* At = (const float*)d_in[0];  // (1024, 20000) row-major
  const float* b  = (const float*)d_in[1];
  const float* w1 = (const float*)d_in[2];
  const float* W2 = (const float*)d_in[3];  // (512, 1023) row-major
  float* out = (float*)d_out;
  float* ws = (float*)d_ws;

  float* gram  = ws + OFF_GRAM;
  float* Zr    = ws + OFF_ZR;
  float* Z1    = ws + OFF_Z1;
  float* S1    = ws + OFF_S1;
  float* S2    = ws + OFF_S2;
  float* scalp = ws + OFF_SCLP;
  float* acc   = ws + OFF_ACC;
  float* tvec  = ws + OFF_TV;
  float* x0ws  = ws + OFF_X0;

  k_init<<<dim3(53), dim3(1024), 0, stream>>>(At, b, w1, W2, out, scalp, x0ws);
  k_gram<<<dim3(NCH), dim3(1024), 0, stream>>>(At, b, x0ws, gram, Zr, scalp,
                                               acc);
  k_scan<<<dim3(32), dim3(1024), 0, stream>>>(Zr, S1);
  k_term<false><<<dim3(NCH), dim3(1024), 0, stream>>>(At, b, gram, S1, Z1, acc,
                                                      tvec, out);
  k_scan<<<dim3(32), dim3(1024), 0, stream>>>(Z1, S2);
  k_term<true><<<dim3(NCH), dim3(1024), 0, stream>>>(At, b, gram, S2, Z1, acc,
                                                     tvec, out);
}